// Round 5
// baseline (212.056 us; speedup 1.0000x reference)
//
#include <hip/hip_runtime.h>

#define HW 4096
#define EPSV 1e-5f
#define SCL (0.125f * 1.44269504088896341f)   // 1/sqrt(64) * log2(e): softmax in exp2 domain

typedef unsigned short u16;
typedef unsigned int u32;
typedef __attribute__((ext_vector_type(8))) short short8;    // 8 bf16 (K=32 frag)
typedef __attribute__((ext_vector_type(4))) short short4v;   // 4 bf16 (K=16 frag)
typedef __attribute__((ext_vector_type(4))) float f32x4;     // C/D frag

#define MFMA_K32(a, b, c) __builtin_amdgcn_mfma_f32_16x16x32_bf16((a), (b), (c), 0, 0, 0)
#if __has_builtin(__builtin_amdgcn_mfma_f32_16x16x16bf16_1k)
#define MFMA_K16(a, b, c) __builtin_amdgcn_mfma_f32_16x16x16bf16_1k((a), (b), (c), 0, 0, 0)
#elif __has_builtin(__builtin_amdgcn_mfma_f32_16x16x16_bf16)
#define MFMA_K16(a, b, c) __builtin_amdgcn_mfma_f32_16x16x16_bf16((a), (b), (c), 0, 0, 0)
#else
// Host-pass parse stub only: the device pass selects a real builtin above.
#define MFMA_K16(a, b, c) (c)
#endif

#define GLDS(g, l) __builtin_amdgcn_global_load_lds( \
    (const __attribute__((address_space(1))) u16*)(g), \
    (__attribute__((address_space(3))) u16*)(l), 16, 0, 0)

__device__ __forceinline__ u16 f2b(float f) {
    u32 u = __float_as_uint(f);
    u32 r = (u + 0x7FFFu + ((u >> 16) & 1u)) >> 16;
    return (u16)r;
}

// ---------------- GroupNorm stage A: 512 blocks, partial sums (+ mask passthrough) ----------------
__global__ __launch_bounds__(256) void gn_partial(const float* __restrict__ x, float* __restrict__ ps,
                                                  const float* __restrict__ mask, float* __restrict__ outm) {
    int bid = blockIdx.x;
    int t = threadIdx.x;
    // fold mask passthrough (16384 floats) into the first 16 blocks
    if (bid < 16) {
        ((float4*)outm)[bid * 256 + t] = ((const float4*)mask)[bid * 256 + t];
    }
    const float4* base = (const float4*)x + (size_t)bid * 2048;
    float s = 0.f, sq = 0.f;
    for (int i = t; i < 2048; i += 256) {
        float4 v = base[i];
        s += v.x + v.y + v.z + v.w;
        sq += v.x * v.x + v.y * v.y + v.z * v.z + v.w * v.w;
    }
    __shared__ float rs[256], rq[256];
    rs[t] = s; rq[t] = sq;
    __syncthreads();
    for (int o = 128; o > 0; o >>= 1) {
        if (t < o) { rs[t] += rs[t + o]; rq[t] += rq[t + o]; }
        __syncthreads();
    }
    if (t == 0) { ps[2 * bid] = rs[0]; ps[2 * bid + 1] = rq[0]; }
}

// ---------------- prep: gn_final (block 0) + wconv qkv (blocks 1..192) + wconv proj (193..256) ----------------
__global__ __launch_bounds__(256) void prep(const float* __restrict__ ps, float* __restrict__ stats,
                                            const float* __restrict__ qkv_w, u16* __restrict__ Wqb,
                                            const float* __restrict__ proj_w, u16* __restrict__ Wpb) {
    int bid = blockIdx.x;
    int t = threadIdx.x;
    if (bid == 0) {
        if (t < 32) {
            float s = 0.f, sq = 0.f;
            for (int i = 0; i < 16; i++) {
                s += ps[2 * (t * 16 + i)];
                sq += ps[2 * (t * 16 + i) + 1];
            }
            float mean = s * (1.f / 131072.f);
            float var = sq * (1.f / 131072.f) - mean * mean;
            stats[t] = mean;
            stats[32 + t] = rsqrtf(var + EPSV);
        }
        return;
    }
    const float* src; u16* dst; int nscaled; int idx;
    if (bid <= 192) { src = qkv_w; dst = Wqb; nscaled = 256; idx = (bid - 1) * 256 + t; }
    else            { src = proj_w; dst = Wpb; nscaled = 0;   idx = (bid - 193) * 256 + t; }
    int row = idx >> 6;
    float sc = (row < nscaled) ? SCL : 1.0f;
    float4 v = *((const float4*)src + idx);
    u32 lo = (u32)f2b(v.x * sc) | ((u32)f2b(v.y * sc) << 16);
    u32 hi = (u32)f2b(v.z * sc) | ((u32)f2b(v.w * sc) << 16);
    uint2 o; o.x = lo; o.y = hi;
    *(uint2*)(dst + (size_t)idx * 4) = o;
}

// ---------------- GroupNorm apply + transpose -> bf16 xt[n][p][c] ----------------
__global__ __launch_bounds__(256) void gn_apply_t(const float* __restrict__ x, const float* __restrict__ w,
                                                  const float* __restrict__ b, const float* __restrict__ stats,
                                                  u16* __restrict__ xt) {
    __shared__ u16 Tt[64][72];
    int t = threadIdx.x;
    int p0 = blockIdx.x * 64;
    int c0 = blockIdx.y * 64;
    int n = blockIdx.z;
    int pc = (t & 15) * 4;
#pragma unroll
    for (int jj = 0; jj < 4; jj++) {
        int r = (t >> 4) + jj * 16;
        int c = c0 + r;
        int grp = n * 8 + (c >> 5);
        float mean = stats[grp], rstd = stats[32 + grp];
        float a = rstd * w[c];
        float bb = b[c] - mean * a;
        float4 v = *(const float4*)(x + ((size_t)n * 256 + c) * HW + p0 + pc);
        Tt[pc + 0][r] = f2b(v.x * a + bb);
        Tt[pc + 1][r] = f2b(v.y * a + bb);
        Tt[pc + 2][r] = f2b(v.z * a + bb);
        Tt[pc + 3][r] = f2b(v.w * a + bb);
    }
    __syncthreads();
    int p = t >> 2, ck = t & 3;
    short8 s0 = *(const short8*)&Tt[p][ck * 16];
    short8 s1 = *(const short8*)&Tt[p][ck * 16 + 8];
    u16* dst = xt + ((size_t)n * HW + p0 + p) * 256 + c0 + ck * 16;
    *(short8*)dst = s0;
    *(short8*)(dst + 8) = s1;
}

// ---------------- QKV MFMA GEMM: X staged once, 12 o-tiles looped with A prefetch ----------------
__global__ __launch_bounds__(256) void qkv_mfma(const u16* __restrict__ xt, const u16* __restrict__ Wb,
                                                const float* __restrict__ bq, u16* __restrict__ Qw,
                                                u16* __restrict__ Kw, u16* __restrict__ Vw) {
    __shared__ u16 Xs[64 * 256];   // [p][c], chunk c/8 xor-swizzled by p&7
    int t = threadIdx.x;
    int w = t >> 6, lane = t & 63;
    int col = lane & 15, quad = lane >> 4;
    int p0 = blockIdx.x * 64;
    int n = blockIdx.z;

#pragma unroll
    for (int j = 0; j < 8; j++) {
        int rl = j * 2 + (lane >> 5);
        int row = w * 16 + rl;
        int slot = (lane & 31) ^ (rl & 7);
        GLDS(xt + ((size_t)n * HW + p0 + row) * 256 + slot * 8, Xs + (w * 16 + j * 2) * 256);
    }

    const u16* wrow = Wb + (size_t)(w * 16 + col) * 256 + quad * 8;
    short8 A[8];
#pragma unroll
    for (int ks = 0; ks < 8; ks++) A[ks] = *(const short8*)(wrow + ks * 32);

    __syncthreads();

    int c7 = col & 7;
    for (int ot = 0; ot < 12; ot++) {
        int o0 = ot * 64;
        // prefetch next o-tile's W fragments before this tile's MFMAs
        short8 An[8];
        if (ot < 11) {
            const u16* wn = wrow + (size_t)(o0 + 64) * 256;
#pragma unroll
            for (int ks = 0; ks < 8; ks++) An[ks] = *(const short8*)(wn + ks * 32);
        }

        f32x4 C[4];
#pragma unroll
        for (int pb = 0; pb < 4; pb++) C[pb] = (f32x4){0.f, 0.f, 0.f, 0.f};
#pragma unroll
        for (int pb = 0; pb < 4; pb++) {
            const u16* xr = Xs + (pb * 16 + col) * 256;
#pragma unroll
            for (int ks = 0; ks < 8; ks++) {
                int slot = (ks * 4 + quad) ^ c7;
                short8 Bf = *(const short8*)(xr + slot * 8);
                C[pb] = MFMA_K32(A[ks], Bf, C[pb]);
            }
        }

        int type = o0 >> 8;
        int h = (o0 >> 6) & 3;
        int nh = n * 4 + h;
        float sc = (type == 0) ? SCL : 1.0f;
        if (type == 2) {
#pragma unroll
            for (int rg = 0; rg < 4; rg++) {
                int d = w * 16 + quad * 4 + rg;
                float bias = bq[o0 + d];
                u16* vb = Vw + ((size_t)nh * 64 + d) * HW + p0 + col;
#pragma unroll
                for (int pb = 0; pb < 4; pb++)
                    vb[pb * 16] = f2b(C[pb][rg] + bias);
            }
        } else {
            u16* dst = (type == 0 ? Qw : Kw) + ((size_t)nh * HW + p0 + col) * 64 + w * 16 + quad * 4;
            float b0 = sc * bq[o0 + w * 16 + quad * 4 + 0];
            float b1 = sc * bq[o0 + w * 16 + quad * 4 + 1];
            float b2 = sc * bq[o0 + w * 16 + quad * 4 + 2];
            float b3 = sc * bq[o0 + w * 16 + quad * 4 + 3];
#pragma unroll
            for (int pb = 0; pb < 4; pb++) {
                uint2 o;
                o.x = (u32)f2b(C[pb][0] + b0) | ((u32)f2b(C[pb][1] + b1) << 16);
                o.y = (u32)f2b(C[pb][2] + b2) | ((u32)f2b(C[pb][3] + b3) << 16);
                *(uint2*)(dst + (size_t)(pb * 16) * 64) = o;
            }
        }
#pragma unroll
        for (int ks = 0; ks < 8; ks++) A[ks] = An[ks];
    }
}

// ---------------- MFMA flash attention v10: 4 q-groups/wave (2x work per LDS byte) ----------------
// grid (16 q-tiles of 256, 16 nh) = 256 blocks (1/CU), block 512 (8 waves), in-block
// j-split (halves), j-tile 64, counted-vmcnt 2-barrier pipeline (R4-verified structure).
// R4 PMC analysis: CU-shared LDS pipe was ~50 us of the 97 (20 KB/wave-step), MFMA/VALU
// per-SIMD pipes ~10-14 us each. v10 doubles q per wave 32->64 (4 MFMA q-groups): each
// K-frag b128 now feeds 8 MFMAs (was 4), each V-frag b64 feeds 4 (was 2), staging and
// global K/V re-reads halve (16 q-tile blocks/nh instead of 32). LDS floor ~50->~25 us.
// VGPR grows to ~190 (launch_bounds(512,2) allows 256 at 8 waves/CU).
__global__ __launch_bounds__(512, 2) void flash_mfma(const u16* __restrict__ Qw, const u16* __restrict__ Kw,
                                                     const u16* __restrict__ Vw, u16* __restrict__ attnT) {
    __shared__ u16 smem[34816];        // staging: Ks 32KB + Vts 32KB; merge epilogue: 68KB
    u16* KsB = smem;                   // [half*2+buf][j][d], 16B chunks xor-swizzled by j&7
    u16* VtsB = smem + 16384;          // [half*2+buf][d][j], 16B chunks xor-swizzled by d&7
    int t = threadIdx.x;
    int w = t >> 6, lane = t & 63;
    int half = w >> 2, wl = w & 3;
    int col = lane & 15, quad = lane >> 4;
    int q0 = blockIdx.x * 256;
    int nh = blockIdx.y;

    // Q fragments for 4 groups: rows q0 + wl*64 + g*16 + col
    const u16* qp = Qw + ((size_t)nh * HW + q0 + wl * 64 + col) * 64 + quad * 8;
    short8 qf[4][2];
#pragma unroll
    for (int g = 0; g < 4; g++) {
        qf[g][0] = *(const short8*)(qp + g * 1024);
        qf[g][1] = *(const short8*)(qp + g * 1024 + 32);
    }

    f32x4 Oa[4][4];   // [g][db]
    f32x4 lac[4];     // denominator accum per group (all 4 regs equal)
#pragma unroll
    for (int g = 0; g < 4; g++) {
        lac[g] = (f32x4){0.f, 0.f, 0.f, 0.f};
#pragma unroll
        for (int db = 0; db < 4; db++) Oa[g][db] = (f32x4){0.f, 0.f, 0.f, 0.f};
    }

    const u16* kbase = Kw + (size_t)nh * HW * 64;  // [p][d]
    const u16* vbase = Vw + (size_t)nh * 64 * HW;  // [d][p]
    int lrK = lane >> 3;      // row-in-8 for both K and V staging
    int ccK = lane & 7;       // chunk
    size_t kSrc = (size_t)(wl * 8 + lrK) * 64 + (ccK ^ lrK) * 8;
    int jbase = half * 2048;

    // Per half per step: K tile 64x64 (8 KB) = 2 GLDS/wave; V^T tile 64x64 = 2 GLDS/wave.
#define STAGE(jt_, b_) do { \
        int j0_ = jbase + (jt_) * 64; \
        _Pragma("unroll") \
        for (int s_ = 0; s_ < 2; s_++) \
            GLDS(kbase + (size_t)j0_ * 64 + kSrc + (size_t)(s_ * 32) * 64, KsB + (half * 2 + (b_)) * 4096 + (wl * 8 + s_ * 32) * 64); \
        _Pragma("unroll") \
        for (int s_ = 0; s_ < 2; s_++) { \
            int d_ = wl * 8 + s_ * 32 + lrK; \
            GLDS(vbase + (size_t)d_ * HW + j0_ + ((ccK ^ lrK) * 8), VtsB + (half * 2 + (b_)) * 4096 + (wl * 8 + s_ * 32) * 64); \
        } \
    } while (0)

    STAGE(0, 0);
    STAGE(1, 1);

    int c7 = col & 7;
    const short4v ones = {0x3F80, 0x3F80, 0x3F80, 0x3F80};  // bf16 1.0 x4
    for (int jt = 0; jt < 32; jt++) {
        int cur = jt & 1;
        // this tile's 4 loads landed; up to 4 newer (tile jt+1) stay in flight
        if (jt < 31) { asm volatile("s_waitcnt vmcnt(4)" ::: "memory"); }
        else         { asm volatile("s_waitcnt vmcnt(0)" ::: "memory"); }
        __builtin_amdgcn_s_barrier();

        const u16* KsC = KsB + (half * 2 + cur) * 4096;
        const u16* VtC = VtsB + (half * 2 + cur) * 4096;

        // S^T for 4 q-groups; K-frags read once per jb, feed 8 MFMAs each
        f32x4 s[4][4];   // [jb][g]
        __builtin_amdgcn_s_setprio(1);
#pragma unroll
        for (int jb = 0; jb < 4; jb++) {
            const u16* kr = KsC + (jb * 16 + col) * 64;
            short8 ka0 = *(const short8*)(kr + ((quad ^ c7) * 8));
            short8 ka1 = *(const short8*)(kr + (((quad + 4) ^ c7) * 8));
#pragma unroll
            for (int g = 0; g < 4; g++) {
                f32x4 a = (f32x4){0.f, 0.f, 0.f, 0.f};
                a = MFMA_K32(ka0, qf[g][0], a);
                a = MFMA_K32(ka1, qf[g][1], a);
                s[jb][g] = a;
            }
        }
        __builtin_amdgcn_s_setprio(0);

        // maxless softmax: p = exp2(s); bf16 round (+0x8000) + v_perm pack
        short4v pt[4][4];   // [g][jb]
#pragma unroll
        for (int jb = 0; jb < 4; jb++) {
#pragma unroll
            for (int g = 0; g < 4; g++) {
                u32 ua[4];
#pragma unroll
                for (int rg = 0; rg < 4; rg++)
                    ua[rg] = __float_as_uint(__builtin_amdgcn_exp2f(s[jb][g][rg])) + 0x8000u;
                uint2 p2;
                p2.x = __builtin_amdgcn_perm(ua[1], ua[0], 0x07060302u);
                p2.y = __builtin_amdgcn_perm(ua[3], ua[2], 0x07060302u);
                pt[g][jb] = __builtin_bit_cast(short4v, p2);
            }
        }

        // denominator + O^T += V^T · P^T; V-frags read once per (db,jb), feed 4 MFMAs
        __builtin_amdgcn_s_setprio(1);
#pragma unroll
        for (int g = 0; g < 4; g++)
#pragma unroll
            for (int jb = 0; jb < 4; jb++)
                lac[g] = MFMA_K16(ones, pt[g][jb], lac[g]);
#pragma unroll
        for (int db = 0; db < 4; db++) {
            const u16* vr = VtC + (db * 16 + col) * 64;
#pragma unroll
            for (int jb = 0; jb < 4; jb++) {
                int ch = jb * 2 + (quad >> 1);
                short4v va = *(const short4v*)(vr + ((ch ^ c7) * 8) + (quad & 1) * 4);
#pragma unroll
                for (int g = 0; g < 4; g++)
                    Oa[g][db] = MFMA_K16(va, pt[g][jb], Oa[g][db]);
            }
        }
        __builtin_amdgcn_s_setprio(0);

        __builtin_amdgcn_s_barrier();   // all waves done reading cur
        if (jt < 30) STAGE(jt + 2, cur);
    }
#undef STAGE

    // ---- half-merge through LDS (loop ended on a barrier; staging buffers are free) ----
    float* mO = (float*)smem;            // [64][256] f32 = 64 KB, lane-consecutive (conflict-free)
    float* mL = (float*)smem + 16384;    // [4][256] f32 = 4 KB (beyond staging region)
    int widx = wl * 64 + lane;
    if (half == 1) {
#pragma unroll
        for (int g = 0; g < 4; g++) {
#pragma unroll
            for (int db = 0; db < 4; db++)
#pragma unroll
                for (int rg = 0; rg < 4; rg++)
                    mO[((g * 4 + db) * 4 + rg) * 256 + widx] = Oa[g][db][rg];
            mL[g * 256 + widx] = lac[g][0];
        }
    }
    __syncthreads();
    if (half == 0) {
#pragma unroll
        for (int g = 0; g < 4; g++) {
            float l = lac[g][0] + mL[g * 256 + widx];
            float rl = 1.0f / l;
            // attnT bf16 [n][q][c], q = q0+wl*64+g*16+col, c = h*64 + db*16 + quad*4 + rg
            u16* ab = attnT + ((size_t)(nh >> 2) * HW + q0 + wl * 64 + g * 16 + col) * 256 + (nh & 3) * 64 + quad * 4;
#pragma unroll
            for (int db = 0; db < 4; db++) {
                float o0v = Oa[g][db][0] + mO[((g * 4 + db) * 4 + 0) * 256 + widx];
                float o1v = Oa[g][db][1] + mO[((g * 4 + db) * 4 + 1) * 256 + widx];
                float o2v = Oa[g][db][2] + mO[((g * 4 + db) * 4 + 2) * 256 + widx];
                float o3v = Oa[g][db][3] + mO[((g * 4 + db) * 4 + 3) * 256 + widx];
                uint2 o;
                o.x = (u32)f2b(o0v * rl) | ((u32)f2b(o1v * rl) << 16);
                o.y = (u32)f2b(o2v * rl) | ((u32)f2b(o3v * rl) << 16);
                *(uint2*)(ab + db * 16) = o;
            }
        }
    }
}

// ---------------- Proj MFMA GEMM + bias + residual + mask: attnT staged once, 4 o-tiles ----------------
__global__ __launch_bounds__(256) void proj_mfma(const u16* __restrict__ attnT, const u16* __restrict__ Wpb,
                                                 const float* __restrict__ bp, const float* __restrict__ x,
                                                 const float* __restrict__ mask, float* __restrict__ out) {
    __shared__ u16 Xs[64 * 256];
    int t = threadIdx.x;
    int w = t >> 6, lane = t & 63;
    int col = lane & 15, quad = lane >> 4;
    int p0 = blockIdx.x * 64;
    int n = blockIdx.z;

#pragma unroll
    for (int j = 0; j < 8; j++) {
        int rl = j * 2 + (lane >> 5);
        int row = w * 16 + rl;
        int slot = (lane & 31) ^ (rl & 7);
        GLDS(attnT + ((size_t)n * HW + p0 + row) * 256 + slot * 8, Xs + (w * 16 + j * 2) * 256);
    }

    const u16* wrow = Wpb + (size_t)(w * 16 + col) * 256 + quad * 8;
    short8 A[8];
#pragma unroll
    for (int ks = 0; ks < 8; ks++) A[ks] = *(const short8*)(wrow + ks * 32);

    __syncthreads();

    int c7 = col & 7;
    for (int ot = 0; ot < 4; ot++) {
        int o0 = ot * 64;
        short8 An[8];
        if (ot < 3) {
            const u16* wn = wrow + (size_t)(o0 + 64) * 256;
#pragma unroll
            for (int ks = 0; ks < 8; ks++) An[ks] = *(const short8*)(wn + ks * 32);
        }

        f32x4 C[4];
#pragma unroll
        for (int pb = 0; pb < 4; pb++) C[pb] = (f32x4){0.f, 0.f, 0.f, 0.f};
#pragma unroll
        for (int pb = 0; pb < 4; pb++) {
            const u16* xr = Xs + (pb * 16 + col) * 256;
#pragma unroll
            for (int ks = 0; ks < 8; ks++) {
                int slot = (ks * 4 + quad) ^ c7;
                short8 Bf = *(const short8*)(xr + slot * 8);
                C[pb] = MFMA_K32(A[ks], Bf, C[pb]);
            }
        }

#pragma unroll
        for (int rg = 0; rg < 4; rg++) {
            int o = o0 + w * 16 + quad * 4 + rg;
            float bias = bp[o];
            const float* xb = x + ((size_t)n * 256 + o) * HW + p0 + col;
            float* ob = out + ((size_t)n * 256 + o) * HW + p0 + col;
            const float* mb = mask + (size_t)n * HW + p0 + col;
#pragma unroll
            for (int pb = 0; pb < 4; pb++) {
                float mv = mb[pb * 16];
                ob[pb * 16] = (xb[pb * 16] + C[pb][rg] + bias) * mv;
            }
        }
#pragma unroll
        for (int ks = 0; ks < 8; ks++) A[ks] = An[ks];
    }
}

extern "C" void kernel_launch(void* const* d_in, const int* in_sizes, int n_in,
                              void* d_out, int out_size, void* d_ws, size_t ws_size,
                              hipStream_t stream) {
    const float* x = (const float*)d_in[0];
    const float* mask = (const float*)d_in[1];
    const float* norm_w = (const float*)d_in[2];
    const float* norm_b = (const float*)d_in[3];
    const float* qkv_w = (const float*)d_in[4];
    const float* qkv_b = (const float*)d_in[5];
    const float* proj_w = (const float*)d_in[6];
    const float* proj_b = (const float*)d_in[7];
    float* out = (float*)d_out;

    float* ws = (float*)d_ws;
    float* stats = ws;                    // 64 f32
    float* pstats = ws + 64;              // 1024 f32
    u16* xt = (u16*)(ws + 2048);          // 4,194,304 u16
    u16* Qw = xt + 4194304;
    u16* Kw = Qw + 4194304;
    u16* Vw = Kw + 4194304;
    u16* attnT = Vw + 4194304;
    u16* Wqb = attnT + 4194304;           // 196,608 u16
    u16* Wpb = Wqb + 196608;              // 65,536 u16

    gn_partial<<<512, 256, 0, stream>>>(x, pstats, mask, out + 4194304);
    prep<<<257, 256, 0, stream>>>(pstats, stats, qkv_w, Wqb, proj_w, Wpb);
    gn_apply_t<<<dim3(64, 4, 4), 256, 0, stream>>>(x, norm_w, norm_b, stats, xt);
    qkv_mfma<<<dim3(64, 1, 4), 256, 0, stream>>>(xt, Wqb, qkv_b, Qw, Kw, Vw);
    flash_mfma<<<dim3(16, 16), 512, 0, stream>>>(Qw, Kw, Vw, attnT);
    proj_mfma<<<dim3(64, 1, 4), 256, 0, stream>>>(attnT, Wpb, proj_b, x, mask, out);
}

// Round 6
// 199.702 us; speedup vs baseline: 1.0619x; 1.0619x over previous
//
#include <hip/hip_runtime.h>

#define HW 4096
#define EPSV 1e-5f
#define SCL (0.125f * 1.44269504088896341f)   // 1/sqrt(64) * log2(e): softmax in exp2 domain

typedef unsigned short u16;
typedef unsigned int u32;
typedef __attribute__((ext_vector_type(8))) short short8;    // 8 bf16 (K=32 frag)
typedef __attribute__((ext_vector_type(4))) short short4v;   // 4 bf16 (K=16 frag)
typedef __attribute__((ext_vector_type(4))) float f32x4;     // C/D frag

#define MFMA_K32(a, b, c) __builtin_amdgcn_mfma_f32_16x16x32_bf16((a), (b), (c), 0, 0, 0)
#if __has_builtin(__builtin_amdgcn_mfma_f32_16x16x16bf16_1k)
#define MFMA_K16(a, b, c) __builtin_amdgcn_mfma_f32_16x16x16bf16_1k((a), (b), (c), 0, 0, 0)
#elif __has_builtin(__builtin_amdgcn_mfma_f32_16x16x16_bf16)
#define MFMA_K16(a, b, c) __builtin_amdgcn_mfma_f32_16x16x16_bf16((a), (b), (c), 0, 0, 0)
#else
// Host-pass parse stub only: the device pass selects a real builtin above.
#define MFMA_K16(a, b, c) (c)
#endif

#define GLDS(g, l) __builtin_amdgcn_global_load_lds( \
    (const __attribute__((address_space(1))) u16*)(g), \
    (__attribute__((address_space(3))) u16*)(l), 16, 0, 0)

__device__ __forceinline__ u16 f2b(float f) {
    u32 u = __float_as_uint(f);
    u32 r = (u + 0x7FFFu + ((u >> 16) & 1u)) >> 16;
    return (u16)r;
}

// ---------------- GroupNorm stage A: 512 blocks, partial sums (+ mask passthrough) ----------------
__global__ __launch_bounds__(256) void gn_partial(const float* __restrict__ x, float* __restrict__ ps,
                                                  const float* __restrict__ mask, float* __restrict__ outm) {
    int bid = blockIdx.x;
    int t = threadIdx.x;
    // fold mask passthrough (16384 floats) into the first 16 blocks
    if (bid < 16) {
        ((float4*)outm)[bid * 256 + t] = ((const float4*)mask)[bid * 256 + t];
    }
    const float4* base = (const float4*)x + (size_t)bid * 2048;
    float s = 0.f, sq = 0.f;
    for (int i = t; i < 2048; i += 256) {
        float4 v = base[i];
        s += v.x + v.y + v.z + v.w;
        sq += v.x * v.x + v.y * v.y + v.z * v.z + v.w * v.w;
    }
    __shared__ float rs[256], rq[256];
    rs[t] = s; rq[t] = sq;
    __syncthreads();
    for (int o = 128; o > 0; o >>= 1) {
        if (t < o) { rs[t] += rs[t + o]; rq[t] += rq[t + o]; }
        __syncthreads();
    }
    if (t == 0) { ps[2 * bid] = rs[0]; ps[2 * bid + 1] = rq[0]; }
}

// ---------------- prep: gn_final (block 0) + wconv qkv (blocks 1..192) + wconv proj (193..256) ----------------
__global__ __launch_bounds__(256) void prep(const float* __restrict__ ps, float* __restrict__ stats,
                                            const float* __restrict__ qkv_w, u16* __restrict__ Wqb,
                                            const float* __restrict__ proj_w, u16* __restrict__ Wpb) {
    int bid = blockIdx.x;
    int t = threadIdx.x;
    if (bid == 0) {
        if (t < 32) {
            float s = 0.f, sq = 0.f;
            for (int i = 0; i < 16; i++) {
                s += ps[2 * (t * 16 + i)];
                sq += ps[2 * (t * 16 + i) + 1];
            }
            float mean = s * (1.f / 131072.f);
            float var = sq * (1.f / 131072.f) - mean * mean;
            stats[t] = mean;
            stats[32 + t] = rsqrtf(var + EPSV);
        }
        return;
    }
    const float* src; u16* dst; int nscaled; int idx;
    if (bid <= 192) { src = qkv_w; dst = Wqb; nscaled = 256; idx = (bid - 1) * 256 + t; }
    else            { src = proj_w; dst = Wpb; nscaled = 0;   idx = (bid - 193) * 256 + t; }
    int row = idx >> 6;
    float sc = (row < nscaled) ? SCL : 1.0f;
    float4 v = *((const float4*)src + idx);
    u32 lo = (u32)f2b(v.x * sc) | ((u32)f2b(v.y * sc) << 16);
    u32 hi = (u32)f2b(v.z * sc) | ((u32)f2b(v.w * sc) << 16);
    uint2 o; o.x = lo; o.y = hi;
    *(uint2*)(dst + (size_t)idx * 4) = o;
}

// ---------------- GroupNorm apply + transpose -> bf16 xt[n][p][c] ----------------
__global__ __launch_bounds__(256) void gn_apply_t(const float* __restrict__ x, const float* __restrict__ w,
                                                  const float* __restrict__ b, const float* __restrict__ stats,
                                                  u16* __restrict__ xt) {
    __shared__ u16 Tt[64][72];
    int t = threadIdx.x;
    int p0 = blockIdx.x * 64;
    int c0 = blockIdx.y * 64;
    int n = blockIdx.z;
    int pc = (t & 15) * 4;
#pragma unroll
    for (int jj = 0; jj < 4; jj++) {
        int r = (t >> 4) + jj * 16;
        int c = c0 + r;
        int grp = n * 8 + (c >> 5);
        float mean = stats[grp], rstd = stats[32 + grp];
        float a = rstd * w[c];
        float bb = b[c] - mean * a;
        float4 v = *(const float4*)(x + ((size_t)n * 256 + c) * HW + p0 + pc);
        Tt[pc + 0][r] = f2b(v.x * a + bb);
        Tt[pc + 1][r] = f2b(v.y * a + bb);
        Tt[pc + 2][r] = f2b(v.z * a + bb);
        Tt[pc + 3][r] = f2b(v.w * a + bb);
    }
    __syncthreads();
    int p = t >> 2, ck = t & 3;
    short8 s0 = *(const short8*)&Tt[p][ck * 16];
    short8 s1 = *(const short8*)&Tt[p][ck * 16 + 8];
    u16* dst = xt + ((size_t)n * HW + p0 + p) * 256 + c0 + ck * 16;
    *(short8*)dst = s0;
    *(short8*)(dst + 8) = s1;
}

// ---------------- QKV MFMA GEMM: X staged once, o-tiles split 2-way across grid.y ----------------
__global__ __launch_bounds__(256) void qkv_mfma(const u16* __restrict__ xt, const u16* __restrict__ Wb,
                                                const float* __restrict__ bq, u16* __restrict__ Qw,
                                                u16* __restrict__ Kw, u16* __restrict__ Vw) {
    __shared__ u16 Xs[64 * 256];   // [p][c], chunk c/8 xor-swizzled by p&7
    int t = threadIdx.x;
    int w = t >> 6, lane = t & 63;
    int col = lane & 15, quad = lane >> 4;
    int p0 = blockIdx.x * 64;
    int oh = blockIdx.y;           // 0: o in [0,384), 1: o in [384,768)
    int n = blockIdx.z;

#pragma unroll
    for (int j = 0; j < 8; j++) {
        int rl = j * 2 + (lane >> 5);
        int row = w * 16 + rl;
        int slot = (lane & 31) ^ (rl & 7);
        GLDS(xt + ((size_t)n * HW + p0 + row) * 256 + slot * 8, Xs + (w * 16 + j * 2) * 256);
    }

    const u16* wrow = Wb + (size_t)(oh * 384 + w * 16 + col) * 256 + quad * 8;
    short8 A[8];
#pragma unroll
    for (int ks = 0; ks < 8; ks++) A[ks] = *(const short8*)(wrow + ks * 32);

    __syncthreads();

    int c7 = col & 7;
    for (int oi = 0; oi < 6; oi++) {
        int o0 = oh * 384 + oi * 64;
        // prefetch next o-tile's W fragments before this tile's MFMAs
        short8 An[8];
        if (oi < 5) {
            const u16* wn = wrow + (size_t)(oi + 1) * 64 * 256;
#pragma unroll
            for (int ks = 0; ks < 8; ks++) An[ks] = *(const short8*)(wn + ks * 32);
        }

        f32x4 C[4];
#pragma unroll
        for (int pb = 0; pb < 4; pb++) C[pb] = (f32x4){0.f, 0.f, 0.f, 0.f};
#pragma unroll
        for (int pb = 0; pb < 4; pb++) {
            const u16* xr = Xs + (pb * 16 + col) * 256;
#pragma unroll
            for (int ks = 0; ks < 8; ks++) {
                int slot = (ks * 4 + quad) ^ c7;
                short8 Bf = *(const short8*)(xr + slot * 8);
                C[pb] = MFMA_K32(A[ks], Bf, C[pb]);
            }
        }

        int type = o0 >> 8;
        int h = (o0 >> 6) & 3;
        int nh = n * 4 + h;
        float sc = (type == 0) ? SCL : 1.0f;
        if (type == 2) {
#pragma unroll
            for (int rg = 0; rg < 4; rg++) {
                int d = w * 16 + quad * 4 + rg;
                float bias = bq[o0 + d];
                u16* vb = Vw + ((size_t)nh * 64 + d) * HW + p0 + col;
#pragma unroll
                for (int pb = 0; pb < 4; pb++)
                    vb[pb * 16] = f2b(C[pb][rg] + bias);
            }
        } else {
            u16* dst = (type == 0 ? Qw : Kw) + ((size_t)nh * HW + p0 + col) * 64 + w * 16 + quad * 4;
            float b0 = sc * bq[o0 + w * 16 + quad * 4 + 0];
            float b1 = sc * bq[o0 + w * 16 + quad * 4 + 1];
            float b2 = sc * bq[o0 + w * 16 + quad * 4 + 2];
            float b3 = sc * bq[o0 + w * 16 + quad * 4 + 3];
#pragma unroll
            for (int pb = 0; pb < 4; pb++) {
                uint2 o;
                o.x = (u32)f2b(C[pb][0] + b0) | ((u32)f2b(C[pb][1] + b1) << 16);
                o.y = (u32)f2b(C[pb][2] + b2) | ((u32)f2b(C[pb][3] + b3) << 16);
                *(uint2*)(dst + (size_t)(pb * 16) * 64) = o;
            }
        }
#pragma unroll
        for (int ks = 0; ks < 8; ks++) A[ks] = An[ks];
    }
}

// ---------------- MFMA flash attention v11: cvt_pk pack + VALU denominator ----------------
// grid (32 q-tiles of 128, 16 nh) = 512 blocks (2/CU), block 512 (8 waves), in-block
// j-split (halves), j-tile 64, counted-vmcnt 2-barrier pipeline (R4-verified structure).
// R4 pipe balance: MFMA 54%, VALU 49%, LDS ~50% -- all three ~equal, occupancy capped
// at 16 waves/CU. v11 cuts work: (1) bf16 pack via v_cvt_pk_bf16_f32 (1 op/pair vs
// add+add+perm: -32 VALU/wave-step); (2) denominator per-lane f32 adds in the exp2 loop
// (v6-verified) instead of 8 ones-MFMA K16s (-14% MFMA); cross-quad shfl_xor once in
// the epilogue. Sync structure, STAGE, layouts byte-identical to R4.
__global__ __launch_bounds__(512, 4) void flash_mfma(const u16* __restrict__ Qw, const u16* __restrict__ Kw,
                                                     const u16* __restrict__ Vw, u16* __restrict__ attnT) {
    __shared__ u16 Ks[4][64 * 64];    // [half*2+buf][j][d], 16B chunks xor-swizzled by j&7
    __shared__ u16 Vts[4][64 * 64];   // [half*2+buf][d][j], 16B chunks xor-swizzled by d&7
    int t = threadIdx.x;
    int w = t >> 6, lane = t & 63;
    int half = w >> 2, wl = w & 3;
    int col = lane & 15, quad = lane >> 4;
    int q0 = blockIdx.x * 128;
    int nh = blockIdx.y;

    // Q fragments for both groups: qA = q0+wl*32+col, qB = qA+16 (same Q in both halves)
    const u16* qp = Qw + ((size_t)nh * HW + q0 + wl * 32 + col) * 64 + quad * 8;
    short8 qa0 = *(const short8*)qp;
    short8 qa1 = *(const short8*)(qp + 32);
    short8 qc0 = *(const short8*)(qp + 1024);
    short8 qc1 = *(const short8*)(qp + 1024 + 32);

    f32x4 OaA[4], OaB[4];
#pragma unroll
    for (int db = 0; db < 4; db++) {
        OaA[db] = (f32x4){0.f, 0.f, 0.f, 0.f};
        OaB[db] = (f32x4){0.f, 0.f, 0.f, 0.f};
    }
    float lacA = 0.f, lacB = 0.f;   // per-lane partial denominators (VALU)

    const u16* kbase = Kw + (size_t)nh * HW * 64;  // [p][d]
    const u16* vbase = Vw + (size_t)nh * 64 * HW;  // [d][p]
    int lrK = lane >> 3;      // row-in-8 for both K and V staging
    int ccK = lane & 7;       // chunk
    size_t kSrc = (size_t)(wl * 8 + lrK) * 64 + (ccK ^ lrK) * 8;
    int jbase = half * 2048;

    // Per half per step: K tile 64x64 (8 KB) = 2 GLDS/wave; V^T tile 64x64 = 2 GLDS/wave.
#define STAGE(jt_, b_) do { \
        int j0_ = jbase + (jt_) * 64; \
        _Pragma("unroll") \
        for (int s_ = 0; s_ < 2; s_++) \
            GLDS(kbase + (size_t)j0_ * 64 + kSrc + (size_t)(s_ * 32) * 64, &Ks[half * 2 + (b_)][(wl * 8 + s_ * 32) * 64]); \
        _Pragma("unroll") \
        for (int s_ = 0; s_ < 2; s_++) { \
            int d_ = wl * 8 + s_ * 32 + lrK; \
            GLDS(vbase + (size_t)d_ * HW + j0_ + ((ccK ^ lrK) * 8), &Vts[half * 2 + (b_)][(wl * 8 + s_ * 32) * 64]); \
        } \
    } while (0)

    STAGE(0, 0);
    STAGE(1, 1);

    int c7 = col & 7;
    for (int jt = 0; jt < 32; jt++) {
        int cur = jt & 1;
        // this tile's 4 loads landed; up to 4 newer (tile jt+1) stay in flight
        if (jt < 31) { asm volatile("s_waitcnt vmcnt(4)" ::: "memory"); }
        else         { asm volatile("s_waitcnt vmcnt(0)" ::: "memory"); }
        __builtin_amdgcn_s_barrier();

        const u16* KsC = Ks[half * 2 + cur];
        const u16* VtC = Vts[half * 2 + cur];

        // S^T for both q-groups; K-frags read once (4 jb of 16 j)
        f32x4 sA[4], sB[4];
        __builtin_amdgcn_s_setprio(1);
#pragma unroll
        for (int jb = 0; jb < 4; jb++) {
            const u16* kr = KsC + (jb * 16 + col) * 64;
            short8 ka0 = *(const short8*)(kr + ((quad ^ c7) * 8));
            short8 ka1 = *(const short8*)(kr + (((quad + 4) ^ c7) * 8));
            f32x4 a = (f32x4){0.f, 0.f, 0.f, 0.f};
            a = MFMA_K32(ka0, qa0, a);
            a = MFMA_K32(ka1, qa1, a);
            sA[jb] = a;
            f32x4 b = (f32x4){0.f, 0.f, 0.f, 0.f};
            b = MFMA_K32(ka0, qc0, b);
            b = MFMA_K32(ka1, qc1, b);
            sB[jb] = b;
        }
        __builtin_amdgcn_s_setprio(0);

        // maxless softmax: p = exp2(s); per-lane l adds; RTNE pack via v_cvt_pk_bf16_f32
        short4v ptA[4], ptB[4];
#pragma unroll
        for (int jb = 0; jb < 4; jb++) {
            float ea0 = __builtin_amdgcn_exp2f(sA[jb][0]);
            float ea1 = __builtin_amdgcn_exp2f(sA[jb][1]);
            float ea2 = __builtin_amdgcn_exp2f(sA[jb][2]);
            float ea3 = __builtin_amdgcn_exp2f(sA[jb][3]);
            float eb0 = __builtin_amdgcn_exp2f(sB[jb][0]);
            float eb1 = __builtin_amdgcn_exp2f(sB[jb][1]);
            float eb2 = __builtin_amdgcn_exp2f(sB[jb][2]);
            float eb3 = __builtin_amdgcn_exp2f(sB[jb][3]);
            lacA += (ea0 + ea1) + (ea2 + ea3);
            lacB += (eb0 + eb1) + (eb2 + eb3);
            uint2 pa2, pb2;
            asm("v_cvt_pk_bf16_f32 %0, %1, %2" : "=v"(pa2.x) : "v"(ea0), "v"(ea1));
            asm("v_cvt_pk_bf16_f32 %0, %1, %2" : "=v"(pa2.y) : "v"(ea2), "v"(ea3));
            asm("v_cvt_pk_bf16_f32 %0, %1, %2" : "=v"(pb2.x) : "v"(eb0), "v"(eb1));
            asm("v_cvt_pk_bf16_f32 %0, %1, %2" : "=v"(pb2.y) : "v"(eb2), "v"(eb3));
            ptA[jb] = __builtin_bit_cast(short4v, pa2);
            ptB[jb] = __builtin_bit_cast(short4v, pb2);
        }

        // O^T += V^T · P^T
        __builtin_amdgcn_s_setprio(1);
#pragma unroll
        for (int db = 0; db < 4; db++) {
            const u16* vr = VtC + (db * 16 + col) * 64;
#pragma unroll
            for (int jb = 0; jb < 4; jb++) {
                int ch = jb * 2 + (quad >> 1);
                short4v va = *(const short4v*)(vr + ((ch ^ c7) * 8) + (quad & 1) * 4);
                OaA[db] = MFMA_K16(va, ptA[jb], OaA[db]);
                OaB[db] = MFMA_K16(va, ptB[jb], OaB[db]);
            }
        }
        __builtin_amdgcn_s_setprio(0);

        __builtin_amdgcn_s_barrier();   // all waves done reading cur
        if (jt < 30) STAGE(jt + 2, cur);
    }
#undef STAGE

    // cross-quad l reduction (lane's partial covers its quad's j rows)
    lacA += __shfl_xor(lacA, 16);
    lacB += __shfl_xor(lacB, 16);
    lacA += __shfl_xor(lacA, 32);
    lacB += __shfl_xor(lacB, 32);

    // ---- half-merge through LDS (loop ended on a barrier; buffers are free) ----
    float* mO = (float*)&Ks[0][0];   // [32][256] f32 = 32 KB, lane-consecutive (conflict-free)
    float* mL = (float*)&Vts[0][0];  // [2][256] f32
    int widx = wl * 64 + lane;
    if (half == 1) {
#pragma unroll
        for (int db = 0; db < 4; db++) {
#pragma unroll
            for (int rg = 0; rg < 4; rg++) {
                mO[(db * 8 + rg) * 256 + widx] = OaA[db][rg];
                mO[(db * 8 + 4 + rg) * 256 + widx] = OaB[db][rg];
            }
        }
        mL[widx] = lacA;
        mL[256 + widx] = lacB;
    }
    __syncthreads();
    if (half == 0) {
        float lA = lacA + mL[widx];
        float lB = lacB + mL[256 + widx];
        float rlA = 1.0f / lA, rlB = 1.0f / lB;
        // epilogue: attnT bf16 [n][q][c], c = h*64 + db*16 + quad*4 + rg -> packed 8B stores
        u16* abA = attnT + ((size_t)(nh >> 2) * HW + q0 + wl * 32 + col) * 256 + (nh & 3) * 64 + quad * 4;
        u16* abB = abA + 16 * 256;
#pragma unroll
        for (int db = 0; db < 4; db++) {
            float a0 = OaA[db][0] + mO[(db * 8 + 0) * 256 + widx];
            float a1 = OaA[db][1] + mO[(db * 8 + 1) * 256 + widx];
            float a2 = OaA[db][2] + mO[(db * 8 + 2) * 256 + widx];
            float a3 = OaA[db][3] + mO[(db * 8 + 3) * 256 + widx];
            float b0 = OaB[db][0] + mO[(db * 8 + 4) * 256 + widx];
            float b1 = OaB[db][1] + mO[(db * 8 + 5) * 256 + widx];
            float b2 = OaB[db][2] + mO[(db * 8 + 6) * 256 + widx];
            float b3 = OaB[db][3] + mO[(db * 8 + 7) * 256 + widx];
            uint2 oA, oB;
            oA.x = (u32)f2b(a0 * rlA) | ((u32)f2b(a1 * rlA) << 16);
            oA.y = (u32)f2b(a2 * rlA) | ((u32)f2b(a3 * rlA) << 16);
            oB.x = (u32)f2b(b0 * rlB) | ((u32)f2b(b1 * rlB) << 16);
            oB.y = (u32)f2b(b2 * rlB) | ((u32)f2b(b3 * rlB) << 16);
            *(uint2*)(abA + db * 16) = oA;
            *(uint2*)(abB + db * 16) = oB;
        }
    }
}

// ---------------- Proj MFMA GEMM + bias + residual + mask: o-tiles split 2-way across grid.y ----------------
__global__ __launch_bounds__(256) void proj_mfma(const u16* __restrict__ attnT, const u16* __restrict__ Wpb,
                                                 const float* __restrict__ bp, const float* __restrict__ x,
                                                 const float* __restrict__ mask, float* __restrict__ out) {
    __shared__ u16 Xs[64 * 256];
    int t = threadIdx.x;
    int w = t >> 6, lane = t & 63;
    int col = lane & 15, quad = lane >> 4;
    int p0 = blockIdx.x * 64;
    int oh = blockIdx.y;           // 0: o in [0,128), 1: o in [128,256)
    int n = blockIdx.z;

#pragma unroll
    for (int j = 0; j < 8; j++) {
        int rl = j * 2 + (lane >> 5);
        int row = w * 16 + rl;
        int slot = (lane & 31) ^ (rl & 7);
        GLDS(attnT + ((size_t)n * HW + p0 + row) * 256 + slot * 8, Xs + (w * 16 + j * 2) * 256);
    }

    const u16* wrow = Wpb + (size_t)(oh * 128 + w * 16 + col) * 256 + quad * 8;
    short8 A[8];
#pragma unroll
    for (int ks = 0; ks < 8; ks++) A[ks] = *(const short8*)(wrow + ks * 32);

    __syncthreads();

    int c7 = col & 7;
    for (int oi = 0; oi < 2; oi++) {
        int o0 = oh * 128 + oi * 64;
        short8 An[8];
        if (oi < 1) {
            const u16* wn = wrow + (size_t)64 * 256;
#pragma unroll
            for (int ks = 0; ks < 8; ks++) An[ks] = *(const short8*)(wn + ks * 32);
        }

        f32x4 C[4];
#pragma unroll
        for (int pb = 0; pb < 4; pb++) C[pb] = (f32x4){0.f, 0.f, 0.f, 0.f};
#pragma unroll
        for (int pb = 0; pb < 4; pb++) {
            const u16* xr = Xs + (pb * 16 + col) * 256;
#pragma unroll
            for (int ks = 0; ks < 8; ks++) {
                int slot = (ks * 4 + quad) ^ c7;
                short8 Bf = *(const short8*)(xr + slot * 8);
                C[pb] = MFMA_K32(A[ks], Bf, C[pb]);
            }
        }

#pragma unroll
        for (int rg = 0; rg < 4; rg++) {
            int o = o0 + w * 16 + quad * 4 + rg;
            float bias = bp[o];
            const float* xb = x + ((size_t)n * 256 + o) * HW + p0 + col;
            float* ob = out + ((size_t)n * 256 + o) * HW + p0 + col;
            const float* mb = mask + (size_t)n * HW + p0 + col;
#pragma unroll
            for (int pb = 0; pb < 4; pb++) {
                float mv = mb[pb * 16];
                ob[pb * 16] = (xb[pb * 16] + C[pb][rg] + bias) * mv;
            }
        }
#pragma unroll
        for (int ks = 0; ks < 8; ks++) A[ks] = An[ks];
    }
}

extern "C" void kernel_launch(void* const* d_in, const int* in_sizes, int n_in,
                              void* d_out, int out_size, void* d_ws, size_t ws_size,
                              hipStream_t stream) {
    const float* x = (const float*)d_in[0];
    const float* mask = (const float*)d_in[1];
    const float* norm_w = (const float*)d_in[2];
    const float* norm_b = (const float*)d_in[3];
    const float* qkv_w = (const float*)d_in[4];
    const float* qkv_b = (const float*)d_in[5];
    const float* proj_w = (const float*)d_in[6];
    const float* proj_b = (const float*)d_in[7];
    float* out = (float*)d_out;

    float* ws = (float*)d_ws;
    float* stats = ws;                    // 64 f32
    float* pstats = ws + 64;              // 1024 f32
    u16* xt = (u16*)(ws + 2048);          // 4,194,304 u16
    u16* Qw = xt + 4194304;
    u16* Kw = Qw + 4194304;
    u16* Vw = Kw + 4194304;
    u16* attnT = Vw + 4194304;
    u16* Wqb = attnT + 4194304;           // 196,608 u16
    u16* Wpb = Wqb + 196608;              // 65,536 u16

    gn_partial<<<512, 256, 0, stream>>>(x, pstats, mask, out + 4194304);
    prep<<<257, 256, 0, stream>>>(pstats, stats, qkv_w, Wqb, proj_w, Wpb);
    gn_apply_t<<<dim3(64, 4, 4), 256, 0, stream>>>(x, norm_w, norm_b, stats, xt);
    qkv_mfma<<<dim3(64, 2, 4), 256, 0, stream>>>(xt, Wqb, qkv_b, Qw, Kw, Vw);
    flash_mfma<<<dim3(32, 16), 512, 0, stream>>>(Qw, Kw, Vw, attnT);
    proj_mfma<<<dim3(64, 2, 4), 256, 0, stream>>>(attnT, Wpb, proj_b, x, mask, out);
}

// Round 7
// 197.813 us; speedup vs baseline: 1.0720x; 1.0096x over previous
//
#include <hip/hip_runtime.h>

#define HW 4096
#define EPSV 1e-5f
#define SCL (0.125f * 1.44269504088896341f)   // 1/sqrt(64) * log2(e): softmax in exp2 domain

typedef unsigned short u16;
typedef unsigned int u32;
typedef __attribute__((ext_vector_type(8))) short short8;    // 8 bf16 (K=32 frag)
typedef __attribute__((ext_vector_type(4))) short short4v;   // 4 bf16 (K=16 frag)
typedef __attribute__((ext_vector_type(4))) float f32x4;     // C/D frag

#define MFMA_K32(a, b, c) __builtin_amdgcn_mfma_f32_16x16x32_bf16((a), (b), (c), 0, 0, 0)
#if __has_builtin(__builtin_amdgcn_mfma_f32_16x16x16bf16_1k)
#define MFMA_K16(a, b, c) __builtin_amdgcn_mfma_f32_16x16x16bf16_1k((a), (b), (c), 0, 0, 0)
#elif __has_builtin(__builtin_amdgcn_mfma_f32_16x16x16_bf16)
#define MFMA_K16(a, b, c) __builtin_amdgcn_mfma_f32_16x16x16_bf16((a), (b), (c), 0, 0, 0)
#else
// Host-pass parse stub only: the device pass selects a real builtin above.
#define MFMA_K16(a, b, c) (c)
#endif

#define GLDS(g, l) __builtin_amdgcn_global_load_lds( \
    (const __attribute__((address_space(1))) u16*)(g), \
    (__attribute__((address_space(3))) u16*)(l), 16, 0, 0)

__device__ __forceinline__ u16 f2b(float f) {
    u32 u = __float_as_uint(f);
    u32 r = (u + 0x7FFFu + ((u >> 16) & 1u)) >> 16;
    return (u16)r;
}

// ---- Kernel 1: GroupNorm partial sums + weight conversion + mask passthrough (512 blocks) ----
// blocks 0-15 additionally copy mask; blocks 0-191 convert qkv_w; 192-255 convert proj_w;
// all 512 compute x partial sums for their 2-channel slice -> ps[2*bid].
__global__ __launch_bounds__(256) void gn_wprep(const float* __restrict__ x, float* __restrict__ ps,
                                                const float* __restrict__ mask, float* __restrict__ outm,
                                                const float* __restrict__ qkv_w, u16* __restrict__ Wqb,
                                                const float* __restrict__ proj_w, u16* __restrict__ Wpb) {
    int bid = blockIdx.x;
    int t = threadIdx.x;
    if (bid < 16) {
        ((float4*)outm)[bid * 256 + t] = ((const float4*)mask)[bid * 256 + t];
    }
    if (bid < 256) {
        const float* src; u16* dst; int nscaled; int idx;
        if (bid < 192) { src = qkv_w; dst = Wqb; nscaled = 256; idx = bid * 256 + t; }
        else           { src = proj_w; dst = Wpb; nscaled = 0;   idx = (bid - 192) * 256 + t; }
        int row = idx >> 6;
        float sc = (row < nscaled) ? SCL : 1.0f;
        float4 v = *((const float4*)src + idx);
        u32 lo = (u32)f2b(v.x * sc) | ((u32)f2b(v.y * sc) << 16);
        u32 hi = (u32)f2b(v.z * sc) | ((u32)f2b(v.w * sc) << 16);
        uint2 o; o.x = lo; o.y = hi;
        *(uint2*)(dst + (size_t)idx * 4) = o;
    }
    const float4* base = (const float4*)x + (size_t)bid * 2048;
    float s = 0.f, sq = 0.f;
    for (int i = t; i < 2048; i += 256) {
        float4 v = base[i];
        s += v.x + v.y + v.z + v.w;
        sq += v.x * v.x + v.y * v.y + v.z * v.z + v.w * v.w;
    }
    __shared__ float rs[256], rq[256];
    rs[t] = s; rq[t] = sq;
    __syncthreads();
    for (int o = 128; o > 0; o >>= 1) {
        if (t < o) { rs[t] += rs[t + o]; rq[t] += rq[t + o]; }
        __syncthreads();
    }
    if (t == 0) { ps[2 * bid] = rs[0]; ps[2 * bid + 1] = rq[0]; }
}

// ---- Kernel 2: fused GroupNorm-apply + transpose + QKV GEMM (grid (64,1,4), 256 thr) ----
// Per block: recompute this n's 8 group stats from ps (bitwise-identical to the old
// gn_final: same 16-step order), transform x f32 -> bf16 GroupNorm'd directly into the
// xor-swizzled Xs LDS tile (via the Tt transpose tile), then run the 12-o-tile MFMA loop.
// Deletes the xt global round-trip (8.4 MB write + 16.8 MB read) and two kernel launches.
__global__ __launch_bounds__(256) void qkv_fused(const float* __restrict__ x, const float* __restrict__ ps,
                                                 const float* __restrict__ nw, const float* __restrict__ nb,
                                                 const u16* __restrict__ Wb, const float* __restrict__ bq,
                                                 u16* __restrict__ Qw, u16* __restrict__ Kw, u16* __restrict__ Vw) {
    __shared__ u16 Xs[64 * 256];   // [p][c], chunk c/8 at slot (c/8)^(p&7)
    __shared__ u16 Tt[64][72];
    __shared__ float gm[8], gr[8];
    int t = threadIdx.x;
    int w = t >> 6, lane = t & 63;
    int col = lane & 15, quad = lane >> 4;
    int p0 = blockIdx.x * 64;
    int n = blockIdx.z;

    // A-fragments for o-tile 0: issue global loads first (latency hides under transform)
    const u16* wrow = Wb + (size_t)(w * 16 + col) * 256 + quad * 8;
    short8 A[8];
#pragma unroll
    for (int ks = 0; ks < 8; ks++) A[ks] = *(const short8*)(wrow + ks * 32);

    // group stats (threads 0-7), identical summation order to the old gn_final
    if (t < 8) {
        float s = 0.f, sq = 0.f;
        for (int i = 0; i < 16; i++) {
            s += ps[2 * ((n * 8 + t) * 16 + i)];
            sq += ps[2 * ((n * 8 + t) * 16 + i) + 1];
        }
        float mean = s * (1.f / 131072.f);
        float var = sq * (1.f / 131072.f) - mean * mean;
        gm[t] = mean;
        gr[t] = rsqrtf(var + EPSV);
    }
    __syncthreads();

    // 4 transform passes: x[n][c0+..][p0+..] -> Tt[p][c] -> Xs swizzled
    int pc = (t & 15) * 4;
#pragma unroll
    for (int cb = 0; cb < 4; cb++) {
        int c0 = cb * 64;
#pragma unroll
        for (int jj = 0; jj < 4; jj++) {
            int r = (t >> 4) + jj * 16;
            int c = c0 + r;
            int g = c >> 5;
            float a = gr[g] * nw[c];
            float bb = nb[c] - gm[g] * a;
            float4 v = *(const float4*)(x + ((size_t)n * 256 + c) * HW + p0 + pc);
            Tt[pc + 0][r] = f2b(v.x * a + bb);
            Tt[pc + 1][r] = f2b(v.y * a + bb);
            Tt[pc + 2][r] = f2b(v.z * a + bb);
            Tt[pc + 3][r] = f2b(v.w * a + bb);
        }
        __syncthreads();
        int p = t >> 2, ck = t & 3;
        short8 s0 = *(const short8*)&Tt[p][ck * 16];
        short8 s1 = *(const short8*)&Tt[p][ck * 16 + 8];
        int ch0 = cb * 8 + ck * 2;
        *(short8*)(Xs + p * 256 + ((ch0 ^ (p & 7)) * 8)) = s0;
        *(short8*)(Xs + p * 256 + (((ch0 + 1) ^ (p & 7)) * 8)) = s1;
        __syncthreads();
    }

    int c7 = col & 7;
    for (int ot = 0; ot < 12; ot++) {
        int o0 = ot * 64;
        // prefetch next o-tile's W fragments before this tile's MFMAs
        short8 An[8];
        if (ot < 11) {
            const u16* wn = wrow + (size_t)(o0 + 64) * 256;
#pragma unroll
            for (int ks = 0; ks < 8; ks++) An[ks] = *(const short8*)(wn + ks * 32);
        }

        f32x4 C[4];
#pragma unroll
        for (int pb = 0; pb < 4; pb++) C[pb] = (f32x4){0.f, 0.f, 0.f, 0.f};
#pragma unroll
        for (int pb = 0; pb < 4; pb++) {
            const u16* xr = Xs + (pb * 16 + col) * 256;
#pragma unroll
            for (int ks = 0; ks < 8; ks++) {
                int slot = (ks * 4 + quad) ^ c7;
                short8 Bf = *(const short8*)(xr + slot * 8);
                C[pb] = MFMA_K32(A[ks], Bf, C[pb]);
            }
        }

        int type = o0 >> 8;
        int h = (o0 >> 6) & 3;
        int nh = n * 4 + h;
        float sc = (type == 0) ? SCL : 1.0f;
        if (type == 2) {
#pragma unroll
            for (int rg = 0; rg < 4; rg++) {
                int d = w * 16 + quad * 4 + rg;
                float bias = bq[o0 + d];
                u16* vb = Vw + ((size_t)nh * 64 + d) * HW + p0 + col;
#pragma unroll
                for (int pb = 0; pb < 4; pb++)
                    vb[pb * 16] = f2b(C[pb][rg] + bias);
            }
        } else {
            u16* dst = (type == 0 ? Qw : Kw) + ((size_t)nh * HW + p0 + col) * 64 + w * 16 + quad * 4;
            float b0 = sc * bq[o0 + w * 16 + quad * 4 + 0];
            float b1 = sc * bq[o0 + w * 16 + quad * 4 + 1];
            float b2 = sc * bq[o0 + w * 16 + quad * 4 + 2];
            float b3 = sc * bq[o0 + w * 16 + quad * 4 + 3];
#pragma unroll
            for (int pb = 0; pb < 4; pb++) {
                uint2 o;
                o.x = (u32)f2b(C[pb][0] + b0) | ((u32)f2b(C[pb][1] + b1) << 16);
                o.y = (u32)f2b(C[pb][2] + b2) | ((u32)f2b(C[pb][3] + b3) << 16);
                *(uint2*)(dst + (size_t)(pb * 16) * 64) = o;
            }
        }
#pragma unroll
        for (int ks = 0; ks < 8; ks++) A[ks] = An[ks];
    }
}

// ---------------- MFMA flash attention v11 (R6-verified): cvt_pk pack + VALU denominator ----------------
__global__ __launch_bounds__(512, 4) void flash_mfma(const u16* __restrict__ Qw, const u16* __restrict__ Kw,
                                                     const u16* __restrict__ Vw, u16* __restrict__ attnT) {
    __shared__ u16 Ks[4][64 * 64];    // [half*2+buf][j][d], 16B chunks xor-swizzled by j&7
    __shared__ u16 Vts[4][64 * 64];   // [half*2+buf][d][j], 16B chunks xor-swizzled by d&7
    int t = threadIdx.x;
    int w = t >> 6, lane = t & 63;
    int half = w >> 2, wl = w & 3;
    int col = lane & 15, quad = lane >> 4;
    int q0 = blockIdx.x * 128;
    int nh = blockIdx.y;

    // Q fragments for both groups: qA = q0+wl*32+col, qB = qA+16 (same Q in both halves)
    const u16* qp = Qw + ((size_t)nh * HW + q0 + wl * 32 + col) * 64 + quad * 8;
    short8 qa0 = *(const short8*)qp;
    short8 qa1 = *(const short8*)(qp + 32);
    short8 qc0 = *(const short8*)(qp + 1024);
    short8 qc1 = *(const short8*)(qp + 1024 + 32);

    f32x4 OaA[4], OaB[4];
#pragma unroll
    for (int db = 0; db < 4; db++) {
        OaA[db] = (f32x4){0.f, 0.f, 0.f, 0.f};
        OaB[db] = (f32x4){0.f, 0.f, 0.f, 0.f};
    }
    float lacA = 0.f, lacB = 0.f;   // per-lane partial denominators (VALU)

    const u16* kbase = Kw + (size_t)nh * HW * 64;  // [p][d]
    const u16* vbase = Vw + (size_t)nh * 64 * HW;  // [d][p]
    int lrK = lane >> 3;      // row-in-8 for both K and V staging
    int ccK = lane & 7;       // chunk
    size_t kSrc = (size_t)(wl * 8 + lrK) * 64 + (ccK ^ lrK) * 8;
    int jbase = half * 2048;

    // Per half per step: K tile 64x64 (8 KB) = 2 GLDS/wave; V^T tile 64x64 = 2 GLDS/wave.
#define STAGE(jt_, b_) do { \
        int j0_ = jbase + (jt_) * 64; \
        _Pragma("unroll") \
        for (int s_ = 0; s_ < 2; s_++) \
            GLDS(kbase + (size_t)j0_ * 64 + kSrc + (size_t)(s_ * 32) * 64, &Ks[half * 2 + (b_)][(wl * 8 + s_ * 32) * 64]); \
        _Pragma("unroll") \
        for (int s_ = 0; s_ < 2; s_++) { \
            int d_ = wl * 8 + s_ * 32 + lrK; \
            GLDS(vbase + (size_t)d_ * HW + j0_ + ((ccK ^ lrK) * 8), &Vts[half * 2 + (b_)][(wl * 8 + s_ * 32) * 64]); \
        } \
    } while (0)

    STAGE(0, 0);
    STAGE(1, 1);

    int c7 = col & 7;
    for (int jt = 0; jt < 32; jt++) {
        int cur = jt & 1;
        // this tile's 4 loads landed; up to 4 newer (tile jt+1) stay in flight
        if (jt < 31) { asm volatile("s_waitcnt vmcnt(4)" ::: "memory"); }
        else         { asm volatile("s_waitcnt vmcnt(0)" ::: "memory"); }
        __builtin_amdgcn_s_barrier();

        const u16* KsC = Ks[half * 2 + cur];
        const u16* VtC = Vts[half * 2 + cur];

        // S^T for both q-groups; K-frags read once (4 jb of 16 j)
        f32x4 sA[4], sB[4];
        __builtin_amdgcn_s_setprio(1);
#pragma unroll
        for (int jb = 0; jb < 4; jb++) {
            const u16* kr = KsC + (jb * 16 + col) * 64;
            short8 ka0 = *(const short8*)(kr + ((quad ^ c7) * 8));
            short8 ka1 = *(const short8*)(kr + (((quad + 4) ^ c7) * 8));
            f32x4 a = (f32x4){0.f, 0.f, 0.f, 0.f};
            a = MFMA_K32(ka0, qa0, a);
            a = MFMA_K32(ka1, qa1, a);
            sA[jb] = a;
            f32x4 b = (f32x4){0.f, 0.f, 0.f, 0.f};
            b = MFMA_K32(ka0, qc0, b);
            b = MFMA_K32(ka1, qc1, b);
            sB[jb] = b;
        }
        __builtin_amdgcn_s_setprio(0);

        // maxless softmax: p = exp2(s); per-lane l adds; RTNE pack via v_cvt_pk_bf16_f32
        short4v ptA[4], ptB[4];
#pragma unroll
        for (int jb = 0; jb < 4; jb++) {
            float ea0 = __builtin_amdgcn_exp2f(sA[jb][0]);
            float ea1 = __builtin_amdgcn_exp2f(sA[jb][1]);
            float ea2 = __builtin_amdgcn_exp2f(sA[jb][2]);
            float ea3 = __builtin_amdgcn_exp2f(sA[jb][3]);
            float eb0 = __builtin_amdgcn_exp2f(sB[jb][0]);
            float eb1 = __builtin_amdgcn_exp2f(sB[jb][1]);
            float eb2 = __builtin_amdgcn_exp2f(sB[jb][2]);
            float eb3 = __builtin_amdgcn_exp2f(sB[jb][3]);
            lacA += (ea0 + ea1) + (ea2 + ea3);
            lacB += (eb0 + eb1) + (eb2 + eb3);
            uint2 pa2, pb2;
            asm("v_cvt_pk_bf16_f32 %0, %1, %2" : "=v"(pa2.x) : "v"(ea0), "v"(ea1));
            asm("v_cvt_pk_bf16_f32 %0, %1, %2" : "=v"(pa2.y) : "v"(ea2), "v"(ea3));
            asm("v_cvt_pk_bf16_f32 %0, %1, %2" : "=v"(pb2.x) : "v"(eb0), "v"(eb1));
            asm("v_cvt_pk_bf16_f32 %0, %1, %2" : "=v"(pb2.y) : "v"(eb2), "v"(eb3));
            ptA[jb] = __builtin_bit_cast(short4v, pa2);
            ptB[jb] = __builtin_bit_cast(short4v, pb2);
        }

        // O^T += V^T · P^T
        __builtin_amdgcn_s_setprio(1);
#pragma unroll
        for (int db = 0; db < 4; db++) {
            const u16* vr = VtC + (db * 16 + col) * 64;
#pragma unroll
            for (int jb = 0; jb < 4; jb++) {
                int ch = jb * 2 + (quad >> 1);
                short4v va = *(const short4v*)(vr + ((ch ^ c7) * 8) + (quad & 1) * 4);
                OaA[db] = MFMA_K16(va, ptA[jb], OaA[db]);
                OaB[db] = MFMA_K16(va, ptB[jb], OaB[db]);
            }
        }
        __builtin_amdgcn_s_setprio(0);

        __builtin_amdgcn_s_barrier();   // all waves done reading cur
        if (jt < 30) STAGE(jt + 2, cur);
    }
#undef STAGE

    // cross-quad l reduction (lane's partial covers its quad's j rows)
    lacA += __shfl_xor(lacA, 16);
    lacB += __shfl_xor(lacB, 16);
    lacA += __shfl_xor(lacA, 32);
    lacB += __shfl_xor(lacB, 32);

    // ---- half-merge through LDS (loop ended on a barrier; buffers are free) ----
    float* mO = (float*)&Ks[0][0];   // [32][256] f32 = 32 KB, lane-consecutive (conflict-free)
    float* mL = (float*)&Vts[0][0];  // [2][256] f32
    int widx = wl * 64 + lane;
    if (half == 1) {
#pragma unroll
        for (int db = 0; db < 4; db++) {
#pragma unroll
            for (int rg = 0; rg < 4; rg++) {
                mO[(db * 8 + rg) * 256 + widx] = OaA[db][rg];
                mO[(db * 8 + 4 + rg) * 256 + widx] = OaB[db][rg];
            }
        }
        mL[widx] = lacA;
        mL[256 + widx] = lacB;
    }
    __syncthreads();
    if (half == 0) {
        float lA = lacA + mL[widx];
        float lB = lacB + mL[256 + widx];
        float rlA = 1.0f / lA, rlB = 1.0f / lB;
        // epilogue: attnT bf16 [n][q][c], c = h*64 + db*16 + quad*4 + rg -> packed 8B stores
        u16* abA = attnT + ((size_t)(nh >> 2) * HW + q0 + wl * 32 + col) * 256 + (nh & 3) * 64 + quad * 4;
        u16* abB = abA + 16 * 256;
#pragma unroll
        for (int db = 0; db < 4; db++) {
            float a0 = OaA[db][0] + mO[(db * 8 + 0) * 256 + widx];
            float a1 = OaA[db][1] + mO[(db * 8 + 1) * 256 + widx];
            float a2 = OaA[db][2] + mO[(db * 8 + 2) * 256 + widx];
            float a3 = OaA[db][3] + mO[(db * 8 + 3) * 256 + widx];
            float b0 = OaB[db][0] + mO[(db * 8 + 4) * 256 + widx];
            float b1 = OaB[db][1] + mO[(db * 8 + 5) * 256 + widx];
            float b2 = OaB[db][2] + mO[(db * 8 + 6) * 256 + widx];
            float b3 = OaB[db][3] + mO[(db * 8 + 7) * 256 + widx];
            uint2 oA, oB;
            oA.x = (u32)f2b(a0 * rlA) | ((u32)f2b(a1 * rlA) << 16);
            oA.y = (u32)f2b(a2 * rlA) | ((u32)f2b(a3 * rlA) << 16);
            oB.x = (u32)f2b(b0 * rlB) | ((u32)f2b(b1 * rlB) << 16);
            oB.y = (u32)f2b(b2 * rlB) | ((u32)f2b(b3 * rlB) << 16);
            *(uint2*)(abA + db * 16) = oA;
            *(uint2*)(abB + db * 16) = oB;
        }
    }
}

// ---------------- Proj MFMA GEMM + bias + residual + mask: o-tiles split 2-way across grid.y ----------------
__global__ __launch_bounds__(256) void proj_mfma(const u16* __restrict__ attnT, const u16* __restrict__ Wpb,
                                                 const float* __restrict__ bp, const float* __restrict__ x,
                                                 const float* __restrict__ mask, float* __restrict__ out) {
    __shared__ u16 Xs[64 * 256];
    int t = threadIdx.x;
    int w = t >> 6, lane = t & 63;
    int col = lane & 15, quad = lane >> 4;
    int p0 = blockIdx.x * 64;
    int oh = blockIdx.y;           // 0: o in [0,128), 1: o in [128,256)
    int n = blockIdx.z;

#pragma unroll
    for (int j = 0; j < 8; j++) {
        int rl = j * 2 + (lane >> 5);
        int row = w * 16 + rl;
        int slot = (lane & 31) ^ (rl & 7);
        GLDS(attnT + ((size_t)n * HW + p0 + row) * 256 + slot * 8, Xs + (w * 16 + j * 2) * 256);
    }

    const u16* wrow = Wpb + (size_t)(oh * 128 + w * 16 + col) * 256 + quad * 8;
    short8 A[8];
#pragma unroll
    for (int ks = 0; ks < 8; ks++) A[ks] = *(const short8*)(wrow + ks * 32);

    __syncthreads();

    int c7 = col & 7;
    for (int oi = 0; oi < 2; oi++) {
        int o0 = oh * 128 + oi * 64;
        short8 An[8];
        if (oi < 1) {
            const u16* wn = wrow + (size_t)64 * 256;
#pragma unroll
            for (int ks = 0; ks < 8; ks++) An[ks] = *(const short8*)(wn + ks * 32);
        }

        f32x4 C[4];
#pragma unroll
        for (int pb = 0; pb < 4; pb++) C[pb] = (f32x4){0.f, 0.f, 0.f, 0.f};
#pragma unroll
        for (int pb = 0; pb < 4; pb++) {
            const u16* xr = Xs + (pb * 16 + col) * 256;
#pragma unroll
            for (int ks = 0; ks < 8; ks++) {
                int slot = (ks * 4 + quad) ^ c7;
                short8 Bf = *(const short8*)(xr + slot * 8);
                C[pb] = MFMA_K32(A[ks], Bf, C[pb]);
            }
        }

#pragma unroll
        for (int rg = 0; rg < 4; rg++) {
            int o = o0 + w * 16 + quad * 4 + rg;
            float bias = bp[o];
            const float* xb = x + ((size_t)n * 256 + o) * HW + p0 + col;
            float* ob = out + ((size_t)n * 256 + o) * HW + p0 + col;
            const float* mb = mask + (size_t)n * HW + p0 + col;
#pragma unroll
            for (int pb = 0; pb < 4; pb++) {
                float mv = mb[pb * 16];
                ob[pb * 16] = (xb[pb * 16] + C[pb][rg] + bias) * mv;
            }
        }
#pragma unroll
        for (int ks = 0; ks < 8; ks++) A[ks] = An[ks];
    }
}

extern "C" void kernel_launch(void* const* d_in, const int* in_sizes, int n_in,
                              void* d_out, int out_size, void* d_ws, size_t ws_size,
                              hipStream_t stream) {
    const float* x = (const float*)d_in[0];
    const float* mask = (const float*)d_in[1];
    const float* norm_w = (const float*)d_in[2];
    const float* norm_b = (const float*)d_in[3];
    const float* qkv_w = (const float*)d_in[4];
    const float* qkv_b = (const float*)d_in[5];
    const float* proj_w = (const float*)d_in[6];
    const float* proj_b = (const float*)d_in[7];
    float* out = (float*)d_out;

    float* ws = (float*)d_ws;
    float* pstats = ws + 64;              // 1024 f32
    u16* xt = (u16*)(ws + 2048);          // (region kept for layout stability; unused)
    u16* Qw = xt + 4194304;
    u16* Kw = Qw + 4194304;
    u16* Vw = Kw + 4194304;
    u16* attnT = Vw + 4194304;
    u16* Wqb = attnT + 4194304;           // 196,608 u16
    u16* Wpb = Wqb + 196608;              // 65,536 u16

    gn_wprep<<<512, 256, 0, stream>>>(x, pstats, mask, out + 4194304, qkv_w, Wqb, proj_w, Wpb);
    qkv_fused<<<dim3(64, 1, 4), 256, 0, stream>>>(x, pstats, norm_w, norm_b, Wqb, qkv_b, Qw, Kw, Vw);
    flash_mfma<<<dim3(32, 16), 512, 0, stream>>>(Qw, Kw, Vw, attnT);
    proj_mfma<<<dim3(64, 2, 4), 256, 0, stream>>>(attnT, Wpb, proj_b, x, mask, out);
}

// Round 8
// 197.070 us; speedup vs baseline: 1.0760x; 1.0038x over previous
//
#include <hip/hip_runtime.h>

#define HW 4096
#define EPSV 1e-5f
#define SCL (0.125f * 1.44269504088896341f)   // 1/sqrt(64) * log2(e): softmax in exp2 domain

typedef unsigned short u16;
typedef unsigned int u32;
typedef __attribute__((ext_vector_type(8))) short short8;    // 8 bf16 (K=32 frag)
typedef __attribute__((ext_vector_type(4))) short short4v;   // 4 bf16 (K=16 frag)
typedef __attribute__((ext_vector_type(4))) float f32x4;     // C/D frag

#define MFMA_K32(a, b, c) __builtin_amdgcn_mfma_f32_16x16x32_bf16((a), (b), (c), 0, 0, 0)
#if __has_builtin(__builtin_amdgcn_mfma_f32_16x16x16bf16_1k)
#define MFMA_K16(a, b, c) __builtin_amdgcn_mfma_f32_16x16x16bf16_1k((a), (b), (c), 0, 0, 0)
#elif __has_builtin(__builtin_amdgcn_mfma_f32_16x16x16_bf16)
#define MFMA_K16(a, b, c) __builtin_amdgcn_mfma_f32_16x16x16_bf16((a), (b), (c), 0, 0, 0)
#else
// Host-pass parse stub only: the device pass selects a real builtin above.
#define MFMA_K16(a, b, c) (c)
#endif

#define GLDS(g, l) __builtin_amdgcn_global_load_lds( \
    (const __attribute__((address_space(1))) u16*)(g), \
    (__attribute__((address_space(3))) u16*)(l), 16, 0, 0)

__device__ __forceinline__ u16 f2b(float f) {
    u32 u = __float_as_uint(f);
    u32 r = (u + 0x7FFFu + ((u >> 16) & 1u)) >> 16;
    return (u16)r;
}

// ---- Kernel 1: GroupNorm partial sums + weight conversion + mask passthrough (512 blocks) ----
__global__ __launch_bounds__(256) void gn_wprep(const float* __restrict__ x, float* __restrict__ ps,
                                                const float* __restrict__ mask, float* __restrict__ outm,
                                                const float* __restrict__ qkv_w, u16* __restrict__ Wqb,
                                                const float* __restrict__ proj_w, u16* __restrict__ Wpb) {
    int bid = blockIdx.x;
    int t = threadIdx.x;
    if (bid < 16) {
        ((float4*)outm)[bid * 256 + t] = ((const float4*)mask)[bid * 256 + t];
    }
    if (bid < 256) {
        const float* src; u16* dst; int nscaled; int idx;
        if (bid < 192) { src = qkv_w; dst = Wqb; nscaled = 256; idx = bid * 256 + t; }
        else           { src = proj_w; dst = Wpb; nscaled = 0;   idx = (bid - 192) * 256 + t; }
        int row = idx >> 6;
        float sc = (row < nscaled) ? SCL : 1.0f;
        float4 v = *((const float4*)src + idx);
        u32 lo = (u32)f2b(v.x * sc) | ((u32)f2b(v.y * sc) << 16);
        u32 hi = (u32)f2b(v.z * sc) | ((u32)f2b(v.w * sc) << 16);
        uint2 o; o.x = lo; o.y = hi;
        *(uint2*)(dst + (size_t)idx * 4) = o;
    }
    const float4* base = (const float4*)x + (size_t)bid * 2048;
    float s = 0.f, sq = 0.f;
    for (int i = t; i < 2048; i += 256) {
        float4 v = base[i];
        s += v.x + v.y + v.z + v.w;
        sq += v.x * v.x + v.y * v.y + v.z * v.z + v.w * v.w;
    }
    __shared__ float rs[256], rq[256];
    rs[t] = s; rq[t] = sq;
    __syncthreads();
    for (int o = 128; o > 0; o >>= 1) {
        if (t < o) { rs[t] += rs[t + o]; rq[t] += rq[t + o]; }
        __syncthreads();
    }
    if (t == 0) { ps[2 * bid] = rs[0]; ps[2 * bid + 1] = rq[0]; }
}

// ---- Kernel 2: fused GroupNorm-apply + transpose + QKV GEMM (grid (64,1,4), 512 thr, 8 waves) ----
// v2: 8 waves/block (25% occupancy, was 12.5%). All 8 waves cooperate on the single
// transform into Xs (staged once); then wave-half hh processes interleaved o-tiles
// ot = 2*oi + hh (6 each) -- per-wave serial MFMA chain halves, X never re-staged.
__global__ __launch_bounds__(512) void qkv_fused(const float* __restrict__ x, const float* __restrict__ ps,
                                                 const float* __restrict__ nw, const float* __restrict__ nb,
                                                 const u16* __restrict__ Wb, const float* __restrict__ bq,
                                                 u16* __restrict__ Qw, u16* __restrict__ Kw, u16* __restrict__ Vw) {
    __shared__ u16 Xs[64 * 256];   // [p][c], chunk c/8 at slot (c/8)^(p&7)
    __shared__ u16 Tt[64][72];
    __shared__ float gm[8], gr[8];
    int t = threadIdx.x;
    int w = t >> 6, lane = t & 63;
    int hh = w >> 2, wl = w & 3;
    int col = lane & 15, quad = lane >> 4;
    int p0 = blockIdx.x * 64;
    int n = blockIdx.z;

    // A-fragments for this half's first o-tile (ot = hh): issue early, hide under transform
    const u16* wrow = Wb + (size_t)(hh * 64 + wl * 16 + col) * 256 + quad * 8;
    short8 A[8];
#pragma unroll
    for (int ks = 0; ks < 8; ks++) A[ks] = *(const short8*)(wrow + ks * 32);

    // group stats (threads 0-7), identical summation order to the old gn_final
    if (t < 8) {
        float s = 0.f, sq = 0.f;
        for (int i = 0; i < 16; i++) {
            s += ps[2 * ((n * 8 + t) * 16 + i)];
            sq += ps[2 * ((n * 8 + t) * 16 + i) + 1];
        }
        float mean = s * (1.f / 131072.f);
        float var = sq * (1.f / 131072.f) - mean * mean;
        gm[t] = mean;
        gr[t] = rsqrtf(var + EPSV);
    }
    __syncthreads();

    // 4 transform passes over 512 threads: x[n][c0+..][p0+..] -> Tt[p][c] -> Xs swizzled
    int pc = (t & 15) * 4;
#pragma unroll
    for (int cb = 0; cb < 4; cb++) {
        int c0 = cb * 64;
#pragma unroll
        for (int jj = 0; jj < 2; jj++) {
            int r = (t >> 4) + jj * 32;
            int c = c0 + r;
            int g = c >> 5;
            float a = gr[g] * nw[c];
            float bb = nb[c] - gm[g] * a;
            float4 v = *(const float4*)(x + ((size_t)n * 256 + c) * HW + p0 + pc);
            Tt[pc + 0][r] = f2b(v.x * a + bb);
            Tt[pc + 1][r] = f2b(v.y * a + bb);
            Tt[pc + 2][r] = f2b(v.z * a + bb);
            Tt[pc + 3][r] = f2b(v.w * a + bb);
        }
        __syncthreads();
        int p = t >> 3, ck = t & 7;
        short8 s0 = *(const short8*)&Tt[p][ck * 8];
        int ch = cb * 8 + ck;
        *(short8*)(Xs + p * 256 + ((ch ^ (p & 7)) * 8)) = s0;
        __syncthreads();
    }

    int c7 = col & 7;
    for (int oi = 0; oi < 6; oi++) {
        int ot = oi * 2 + hh;
        int o0 = ot * 64;
        // prefetch this half's next o-tile W fragments (+128 o-rows)
        short8 An[8];
        if (oi < 5) {
            const u16* wn = wrow + (size_t)(oi + 1) * 128 * 256;
#pragma unroll
            for (int ks = 0; ks < 8; ks++) An[ks] = *(const short8*)(wn + ks * 32);
        }

        f32x4 C[4];
#pragma unroll
        for (int pb = 0; pb < 4; pb++) C[pb] = (f32x4){0.f, 0.f, 0.f, 0.f};
#pragma unroll
        for (int pb = 0; pb < 4; pb++) {
            const u16* xr = Xs + (pb * 16 + col) * 256;
#pragma unroll
            for (int ks = 0; ks < 8; ks++) {
                int slot = (ks * 4 + quad) ^ c7;
                short8 Bf = *(const short8*)(xr + slot * 8);
                C[pb] = MFMA_K32(A[ks], Bf, C[pb]);
            }
        }

        int type = o0 >> 8;
        int h = (o0 >> 6) & 3;
        int nh = n * 4 + h;
        float sc = (type == 0) ? SCL : 1.0f;
        if (type == 2) {
#pragma unroll
            for (int rg = 0; rg < 4; rg++) {
                int d = wl * 16 + quad * 4 + rg;
                float bias = bq[o0 + d];
                u16* vb = Vw + ((size_t)nh * 64 + d) * HW + p0 + col;
#pragma unroll
                for (int pb = 0; pb < 4; pb++)
                    vb[pb * 16] = f2b(C[pb][rg] + bias);
            }
        } else {
            u16* dst = (type == 0 ? Qw : Kw) + ((size_t)nh * HW + p0 + col) * 64 + wl * 16 + quad * 4;
            float b0 = sc * bq[o0 + wl * 16 + quad * 4 + 0];
            float b1 = sc * bq[o0 + wl * 16 + quad * 4 + 1];
            float b2 = sc * bq[o0 + wl * 16 + quad * 4 + 2];
            float b3 = sc * bq[o0 + wl * 16 + quad * 4 + 3];
#pragma unroll
            for (int pb = 0; pb < 4; pb++) {
                uint2 o;
                o.x = (u32)f2b(C[pb][0] + b0) | ((u32)f2b(C[pb][1] + b1) << 16);
                o.y = (u32)f2b(C[pb][2] + b2) | ((u32)f2b(C[pb][3] + b3) << 16);
                *(uint2*)(dst + (size_t)(pb * 16) * 64) = o;
            }
        }
#pragma unroll
        for (int ks = 0; ks < 8; ks++) A[ks] = An[ks];
    }
}

// ---------------- MFMA flash attention v11 (R6-verified): cvt_pk pack + VALU denominator ----------------
__global__ __launch_bounds__(512, 4) void flash_mfma(const u16* __restrict__ Qw, const u16* __restrict__ Kw,
                                                     const u16* __restrict__ Vw, u16* __restrict__ attnT) {
    __shared__ u16 Ks[4][64 * 64];    // [half*2+buf][j][d], 16B chunks xor-swizzled by j&7
    __shared__ u16 Vts[4][64 * 64];   // [half*2+buf][d][j], 16B chunks xor-swizzled by d&7
    int t = threadIdx.x;
    int w = t >> 6, lane = t & 63;
    int half = w >> 2, wl = w & 3;
    int col = lane & 15, quad = lane >> 4;
    int q0 = blockIdx.x * 128;
    int nh = blockIdx.y;

    // Q fragments for both groups: qA = q0+wl*32+col, qB = qA+16 (same Q in both halves)
    const u16* qp = Qw + ((size_t)nh * HW + q0 + wl * 32 + col) * 64 + quad * 8;
    short8 qa0 = *(const short8*)qp;
    short8 qa1 = *(const short8*)(qp + 32);
    short8 qc0 = *(const short8*)(qp + 1024);
    short8 qc1 = *(const short8*)(qp + 1024 + 32);

    f32x4 OaA[4], OaB[4];
#pragma unroll
    for (int db = 0; db < 4; db++) {
        OaA[db] = (f32x4){0.f, 0.f, 0.f, 0.f};
        OaB[db] = (f32x4){0.f, 0.f, 0.f, 0.f};
    }
    float lacA = 0.f, lacB = 0.f;   // per-lane partial denominators (VALU)

    const u16* kbase = Kw + (size_t)nh * HW * 64;  // [p][d]
    const u16* vbase = Vw + (size_t)nh * 64 * HW;  // [d][p]
    int lrK = lane >> 3;      // row-in-8 for both K and V staging
    int ccK = lane & 7;       // chunk
    size_t kSrc = (size_t)(wl * 8 + lrK) * 64 + (ccK ^ lrK) * 8;
    int jbase = half * 2048;

    // Per half per step: K tile 64x64 (8 KB) = 2 GLDS/wave; V^T tile 64x64 = 2 GLDS/wave.
#define STAGE(jt_, b_) do { \
        int j0_ = jbase + (jt_) * 64; \
        _Pragma("unroll") \
        for (int s_ = 0; s_ < 2; s_++) \
            GLDS(kbase + (size_t)j0_ * 64 + kSrc + (size_t)(s_ * 32) * 64, &Ks[half * 2 + (b_)][(wl * 8 + s_ * 32) * 64]); \
        _Pragma("unroll") \
        for (int s_ = 0; s_ < 2; s_++) { \
            int d_ = wl * 8 + s_ * 32 + lrK; \
            GLDS(vbase + (size_t)d_ * HW + j0_ + ((ccK ^ lrK) * 8), &Vts[half * 2 + (b_)][(wl * 8 + s_ * 32) * 64]); \
        } \
    } while (0)

    STAGE(0, 0);
    STAGE(1, 1);

    int c7 = col & 7;
    for (int jt = 0; jt < 32; jt++) {
        int cur = jt & 1;
        // this tile's 4 loads landed; up to 4 newer (tile jt+1) stay in flight
        if (jt < 31) { asm volatile("s_waitcnt vmcnt(4)" ::: "memory"); }
        else         { asm volatile("s_waitcnt vmcnt(0)" ::: "memory"); }
        __builtin_amdgcn_s_barrier();

        const u16* KsC = Ks[half * 2 + cur];
        const u16* VtC = Vts[half * 2 + cur];

        // S^T for both q-groups; K-frags read once (4 jb of 16 j)
        f32x4 sA[4], sB[4];
        __builtin_amdgcn_s_setprio(1);
#pragma unroll
        for (int jb = 0; jb < 4; jb++) {
            const u16* kr = KsC + (jb * 16 + col) * 64;
            short8 ka0 = *(const short8*)(kr + ((quad ^ c7) * 8));
            short8 ka1 = *(const short8*)(kr + (((quad + 4) ^ c7) * 8));
            f32x4 a = (f32x4){0.f, 0.f, 0.f, 0.f};
            a = MFMA_K32(ka0, qa0, a);
            a = MFMA_K32(ka1, qa1, a);
            sA[jb] = a;
            f32x4 b = (f32x4){0.f, 0.f, 0.f, 0.f};
            b = MFMA_K32(ka0, qc0, b);
            b = MFMA_K32(ka1, qc1, b);
            sB[jb] = b;
        }
        __builtin_amdgcn_s_setprio(0);

        // maxless softmax: p = exp2(s); per-lane l adds; RTNE pack via v_cvt_pk_bf16_f32
        short4v ptA[4], ptB[4];
#pragma unroll
        for (int jb = 0; jb < 4; jb++) {
            float ea0 = __builtin_amdgcn_exp2f(sA[jb][0]);
            float ea1 = __builtin_amdgcn_exp2f(sA[jb][1]);
            float ea2 = __builtin_amdgcn_exp2f(sA[jb][2]);
            float ea3 = __builtin_amdgcn_exp2f(sA[jb][3]);
            float eb0 = __builtin_amdgcn_exp2f(sB[jb][0]);
            float eb1 = __builtin_amdgcn_exp2f(sB[jb][1]);
            float eb2 = __builtin_amdgcn_exp2f(sB[jb][2]);
            float eb3 = __builtin_amdgcn_exp2f(sB[jb][3]);
            lacA += (ea0 + ea1) + (ea2 + ea3);
            lacB += (eb0 + eb1) + (eb2 + eb3);
            uint2 pa2, pb2;
            asm("v_cvt_pk_bf16_f32 %0, %1, %2" : "=v"(pa2.x) : "v"(ea0), "v"(ea1));
            asm("v_cvt_pk_bf16_f32 %0, %1, %2" : "=v"(pa2.y) : "v"(ea2), "v"(ea3));
            asm("v_cvt_pk_bf16_f32 %0, %1, %2" : "=v"(pb2.x) : "v"(eb0), "v"(eb1));
            asm("v_cvt_pk_bf16_f32 %0, %1, %2" : "=v"(pb2.y) : "v"(eb2), "v"(eb3));
            ptA[jb] = __builtin_bit_cast(short4v, pa2);
            ptB[jb] = __builtin_bit_cast(short4v, pb2);
        }

        // O^T += V^T · P^T
        __builtin_amdgcn_s_setprio(1);
#pragma unroll
        for (int db = 0; db < 4; db++) {
            const u16* vr = VtC + (db * 16 + col) * 64;
#pragma unroll
            for (int jb = 0; jb < 4; jb++) {
                int ch = jb * 2 + (quad >> 1);
                short4v va = *(const short4v*)(vr + ((ch ^ c7) * 8) + (quad & 1) * 4);
                OaA[db] = MFMA_K16(va, ptA[jb], OaA[db]);
                OaB[db] = MFMA_K16(va, ptB[jb], OaB[db]);
            }
        }
        __builtin_amdgcn_s_setprio(0);

        __builtin_amdgcn_s_barrier();   // all waves done reading cur
        if (jt < 30) STAGE(jt + 2, cur);
    }
#undef STAGE

    // cross-quad l reduction (lane's partial covers its quad's j rows)
    lacA += __shfl_xor(lacA, 16);
    lacB += __shfl_xor(lacB, 16);
    lacA += __shfl_xor(lacA, 32);
    lacB += __shfl_xor(lacB, 32);

    // ---- half-merge through LDS (loop ended on a barrier; buffers are free) ----
    float* mO = (float*)&Ks[0][0];   // [32][256] f32 = 32 KB, lane-consecutive (conflict-free)
    float* mL = (float*)&Vts[0][0];  // [2][256] f32
    int widx = wl * 64 + lane;
    if (half == 1) {
#pragma unroll
        for (int db = 0; db < 4; db++) {
#pragma unroll
            for (int rg = 0; rg < 4; rg++) {
                mO[(db * 8 + rg) * 256 + widx] = OaA[db][rg];
                mO[(db * 8 + 4 + rg) * 256 + widx] = OaB[db][rg];
            }
        }
        mL[widx] = lacA;
        mL[256 + widx] = lacB;
    }
    __syncthreads();
    if (half == 0) {
        float lA = lacA + mL[widx];
        float lB = lacB + mL[256 + widx];
        float rlA = 1.0f / lA, rlB = 1.0f / lB;
        // epilogue: attnT bf16 [n][q][c], c = h*64 + db*16 + quad*4 + rg -> packed 8B stores
        u16* abA = attnT + ((size_t)(nh >> 2) * HW + q0 + wl * 32 + col) * 256 + (nh & 3) * 64 + quad * 4;
        u16* abB = abA + 16 * 256;
#pragma unroll
        for (int db = 0; db < 4; db++) {
            float a0 = OaA[db][0] + mO[(db * 8 + 0) * 256 + widx];
            float a1 = OaA[db][1] + mO[(db * 8 + 1) * 256 + widx];
            float a2 = OaA[db][2] + mO[(db * 8 + 2) * 256 + widx];
            float a3 = OaA[db][3] + mO[(db * 8 + 3) * 256 + widx];
            float b0 = OaB[db][0] + mO[(db * 8 + 4) * 256 + widx];
            float b1 = OaB[db][1] + mO[(db * 8 + 5) * 256 + widx];
            float b2 = OaB[db][2] + mO[(db * 8 + 6) * 256 + widx];
            float b3 = OaB[db][3] + mO[(db * 8 + 7) * 256 + widx];
            uint2 oA, oB;
            oA.x = (u32)f2b(a0 * rlA) | ((u32)f2b(a1 * rlA) << 16);
            oA.y = (u32)f2b(a2 * rlA) | ((u32)f2b(a3 * rlA) << 16);
            oB.x = (u32)f2b(b0 * rlB) | ((u32)f2b(b1 * rlB) << 16);
            oB.y = (u32)f2b(b2 * rlB) | ((u32)f2b(b3 * rlB) << 16);
            *(uint2*)(abA + db * 16) = oA;
            *(uint2*)(abB + db * 16) = oB;
        }
    }
}

// ---------------- Proj MFMA GEMM + bias + residual + mask: 1 o-tile per block, grid (64,4,4) ----------------
// 1024 blocks = 4/CU x 4 waves = 16 waves/CU (50% occupancy, was 25%): latency-bound regime
// favors occupancy over the extra 2x attnT staging (L2-resident).
__global__ __launch_bounds__(256) void proj_mfma(const u16* __restrict__ attnT, const u16* __restrict__ Wpb,
                                                 const float* __restrict__ bp, const float* __restrict__ x,
                                                 const float* __restrict__ mask, float* __restrict__ out) {
    __shared__ u16 Xs[64 * 256];
    int t = threadIdx.x;
    int w = t >> 6, lane = t & 63;
    int col = lane & 15, quad = lane >> 4;
    int p0 = blockIdx.x * 64;
    int o0 = blockIdx.y * 64;
    int n = blockIdx.z;

#pragma unroll
    for (int j = 0; j < 8; j++) {
        int rl = j * 2 + (lane >> 5);
        int row = w * 16 + rl;
        int slot = (lane & 31) ^ (rl & 7);
        GLDS(attnT + ((size_t)n * HW + p0 + row) * 256 + slot * 8, Xs + (w * 16 + j * 2) * 256);
    }

    const u16* wrow = Wpb + (size_t)(o0 + w * 16 + col) * 256 + quad * 8;
    short8 A[8];
#pragma unroll
    for (int ks = 0; ks < 8; ks++) A[ks] = *(const short8*)(wrow + ks * 32);

    __syncthreads();

    int c7 = col & 7;
    f32x4 C[4];
#pragma unroll
    for (int pb = 0; pb < 4; pb++) C[pb] = (f32x4){0.f, 0.f, 0.f, 0.f};
#pragma unroll
    for (int pb = 0; pb < 4; pb++) {
        const u16* xr = Xs + (pb * 16 + col) * 256;
#pragma unroll
        for (int ks = 0; ks < 8; ks++) {
            int slot = (ks * 4 + quad) ^ c7;
            short8 Bf = *(const short8*)(xr + slot * 8);
            C[pb] = MFMA_K32(A[ks], Bf, C[pb]);
        }
    }

#pragma unroll
    for (int rg = 0; rg < 4; rg++) {
        int o = o0 + w * 16 + quad * 4 + rg;
        float bias = bp[o];
        const float* xb = x + ((size_t)n * 256 + o) * HW + p0 + col;
        float* ob = out + ((size_t)n * 256 + o) * HW + p0 + col;
        const float* mb = mask + (size_t)n * HW + p0 + col;
#pragma unroll
        for (int pb = 0; pb < 4; pb++) {
            float mv = mb[pb * 16];
            ob[pb * 16] = (xb[pb * 16] + C[pb][rg] + bias) * mv;
        }
    }
}

extern "C" void kernel_launch(void* const* d_in, const int* in_sizes, int n_in,
                              void* d_out, int out_size, void* d_ws, size_t ws_size,
                              hipStream_t stream) {
    const float* x = (const float*)d_in[0];
    const float* mask = (const float*)d_in[1];
    const float* norm_w = (const float*)d_in[2];
    const float* norm_b = (const float*)d_in[3];
    const float* qkv_w = (const float*)d_in[4];
    const float* qkv_b = (const float*)d_in[5];
    const float* proj_w = (const float*)d_in[6];
    const float* proj_b = (const float*)d_in[7];
    float* out = (float*)d_out;

    float* ws = (float*)d_ws;
    float* pstats = ws + 64;              // 1024 f32
    u16* xt = (u16*)(ws + 2048);          // (region kept for layout stability; unused)
    u16* Qw = xt + 4194304;
    u16* Kw = Qw + 4194304;
    u16* Vw = Kw + 4194304;
    u16* attnT = Vw + 4194304;
    u16* Wqb = attnT + 4194304;           // 196,608 u16
    u16* Wpb = Wqb + 196608;              // 65,536 u16

    gn_wprep<<<512, 256, 0, stream>>>(x, pstats, mask, out + 4194304, qkv_w, Wqb, proj_w, Wpb);
    qkv_fused<<<dim3(64, 1, 4), 512, 0, stream>>>(x, pstats, norm_w, norm_b, Wqb, qkv_b, Qw, Kw, Vw);
    flash_mfma<<<dim3(32, 16), 512, 0, stream>>>(Qw, Kw, Vw, attnT);
    proj_mfma<<<dim3(64, 4, 4), 256, 0, stream>>>(attnT, Wpb, proj_b, x, mask, out);
}